// Round 6
// baseline (294.728 us; speedup 1.0000x reference)
//
#include <hip/hip_runtime.h>

#define N_NODES 50000
#define N_EDGES 800000
#define D 64
#define CAP 64            // deg ~ Poisson(16); P(deg > 64) ~ 1e-18 per node
#define FILL_BLOCKS 3125  // 800000 / 256
#define GATHER_BLOCKS 12500  // 1 node per wave, 4 waves/block
#define DENSE_BLOCKS 3125    // 4 nodes per wave, grid-stride

// ---------------------------------------------------------------------------
// fill: srcs[tgt*CAP + cursor[tgt]++] = src.  Bucket order irrelevant.
// ---------------------------------------------------------------------------
__global__ __launch_bounds__(256) void fill_kernel(
        const int* __restrict__ src, const int* __restrict__ tgt,
        int* __restrict__ cursor, int* __restrict__ srcs) {
    int e = blockIdx.x * 256 + threadIdx.x;
    int t = tgt[e];
    int pos = atomicAdd(&cursor[t], 1);
    if (pos < CAP) srcs[t * CAP + pos] = src[e];
}

// ---------------------------------------------------------------------------
// gather: h[i] = deg>0 ? data[i] - mean_j data[src_j] : 0      (all fp32)
// (W_lin commutes with the mean and b_lin cancels, so the linear transform
//  is applied afterwards in the dense kernel.)
// One 64-lane wave per node. lane=(q=lane>>4, p=lane&15); each lane gathers
// float4 chunk p of edge 8*batch+q and 8*batch+q+4 -> dwordx4 instrs, 8 rows
// in flight per batch. Bucket indices fetched with ONE coalesced load
// (srcs[lane]) and distributed via __shfl.
// CORRECTNESS: loop bound nbatch=(dgc+7)>>3 is wave-uniform, so ALL 64 lanes
// are active at every __shfl (ds_bpermute returns 0 from exec-masked-off
// source lanes -- round-5 bug). Only the loads are predicated on j<dgc.
// ---------------------------------------------------------------------------
__global__ __launch_bounds__(256) void gather_kernel(
        const float* __restrict__ data,
        const int* __restrict__ cursor,
        const int* __restrict__ srcs,
        float* __restrict__ h) {
    int lane = threadIdx.x;          // 0..63
    int p = lane & 15;
    int q = lane >> 4;
    int r = blockIdx.x * 4 + threadIdx.y;   // 12500*4 == N_NODES exactly

    int dg = cursor[r];              // wave-uniform
    int dgc = dg < CAP ? dg : CAP;
    int bv = srcs[(size_t)r * CAP + lane];   // whole bucket, 1 coalesced load
    float4 own = ((const float4*)(data + (size_t)r * D))[p];

    float4 a0 = {0.f, 0.f, 0.f, 0.f}, a1 = {0.f, 0.f, 0.f, 0.f};
    int nbatch = (dgc + 7) >> 3;     // wave-uniform trip count
    for (int bt = 0; bt < nbatch; bt++) {
        int j0 = bt * 8 + q;
        int j1 = j0 + 4;
        int e0 = __shfl(bv, j0);     // full exec mask here -> always valid
        int e1 = __shfl(bv, j1);
        if (j0 < dgc) {
            float4 v = ((const float4*)(data + (size_t)e0 * D))[p];
            a0.x += v.x; a0.y += v.y; a0.z += v.z; a0.w += v.w;
        }
        if (j1 < dgc) {
            float4 v = ((const float4*)(data + (size_t)e1 * D))[p];
            a1.x += v.x; a1.y += v.y; a1.z += v.z; a1.w += v.w;
        }
    }
    float4 s;
    s.x = a0.x + a1.x; s.y = a0.y + a1.y; s.z = a0.z + a1.z; s.w = a0.w + a1.w;
    s.x += __shfl_xor(s.x, 16); s.x += __shfl_xor(s.x, 32);
    s.y += __shfl_xor(s.y, 16); s.y += __shfl_xor(s.y, 32);
    s.z += __shfl_xor(s.z, 16); s.z += __shfl_xor(s.z, 32);
    s.w += __shfl_xor(s.w, 16); s.w += __shfl_xor(s.w, 32);

    if (q == 0) {
        float inv  = dg > 0 ? 1.0f / (float)dg : 0.0f;
        float mask = dg > 0 ? 1.0f : 0.0f;
        float4 hv;
        hv.x = (own.x - s.x * inv) * mask;
        hv.y = (own.y - s.y * inv) * mask;
        hv.z = (own.z - s.z * inv) * mask;
        hv.w = (own.w - s.w * inv) * mask;
        ((float4*)(h + (size_t)r * D))[p] = hv;
    }
}

// ---------------------------------------------------------------------------
// dense: out = relu( h @ W_lin^T + merge @ W_tr^T + b_tr )
// lane = output column; both weight rows held in 32 float4 VGPRs; h/merge
// rows read as wave-uniform float4 broadcasts. 4 nodes/wave grid-stride to
// amortize the weight preload.
// ---------------------------------------------------------------------------
__global__ __launch_bounds__(256) void dense_kernel(
        const float* __restrict__ h,
        const float* __restrict__ merge,
        const float* __restrict__ W_lin,
        const float* __restrict__ W_tr,
        const float* __restrict__ b_tr,
        float* __restrict__ out) {
    int lane = threadIdx.x;          // output column
    float4 WL[16], WT[16];
    const float4* wl = (const float4*)(W_lin + (size_t)lane * D);
    const float4* wt = (const float4*)(W_tr + (size_t)lane * D);
#pragma unroll
    for (int i = 0; i < 16; i++) { WL[i] = wl[i]; WT[i] = wt[i]; }
    float bias = b_tr[lane];

    for (int r = blockIdx.x * 4 + threadIdx.y; r < N_NODES; r += DENSE_BLOCKS * 4) {
        const float4* hrow = (const float4*)(h + (size_t)r * D);
        const float4* mrow = (const float4*)(merge + (size_t)r * D);
        float acc = bias;
#pragma unroll
        for (int i = 0; i < 16; i++) {
            float4 dv = hrow[i];     // wave-uniform -> broadcast
            acc += dv.x * WL[i].x + dv.y * WL[i].y
                 + dv.z * WL[i].z + dv.w * WL[i].w;
        }
#pragma unroll
        for (int i = 0; i < 16; i++) {
            float4 mv = mrow[i];
            acc += mv.x * WT[i].x + mv.y * WT[i].y
                 + mv.z * WT[i].z + mv.w * WT[i].w;
        }
        out[(size_t)r * D + lane] = acc > 0.f ? acc : 0.f;
    }
}

extern "C" void kernel_launch(void* const* d_in, const int* in_sizes, int n_in,
                              void* d_out, int out_size, void* d_ws, size_t ws_size,
                              hipStream_t stream) {
    const float* data  = (const float*)d_in[0];
    const float* merge = (const float*)d_in[1];
    const int*   src   = (const int*)d_in[2];
    const int*   tgt   = (const int*)d_in[3];
    // d_in[4] = W_lin, d_in[5] = b_lin (cancels in lap), d_in[6] = W_tr,
    // d_in[7] = b_tr
    const float* W_lin = (const float*)d_in[4];
    const float* W_tr  = (const float*)d_in[6];
    const float* b_tr  = (const float*)d_in[7];
    float* out = (float*)d_out;

    // Workspace: cursor [N i32] | srcs [N*CAP i32] | h [N*D f32]
    char* ws = (char*)d_ws;
    size_t o = 0;
    int*   cursor = (int*)(ws + o);   o += (size_t)N_NODES * 4;
    int*   srcs   = (int*)(ws + o);   o += (size_t)N_NODES * CAP * 4;
    float* h      = (float*)(ws + o); o += (size_t)N_NODES * D * 4;

    hipMemsetAsync(cursor, 0, (size_t)N_NODES * 4, stream);

    fill_kernel<<<FILL_BLOCKS, 256, 0, stream>>>(src, tgt, cursor, srcs);

    gather_kernel<<<GATHER_BLOCKS, dim3(64, 4), 0, stream>>>(
        data, cursor, srcs, h);

    dense_kernel<<<DENSE_BLOCKS, dim3(64, 4), 0, stream>>>(
        h, merge, W_lin, W_tr, b_tr, out);
}